// Round 1
// baseline (232.530 us; speedup 1.0000x reference)
//
#include <hip/hip_runtime.h>
#include <math.h>

#define BB 4096
#define LL 50
#define NN 50
#define DD 128
#define STR 136    // LDS row stride in shorts (272 B, 16B-aligned rows, bank-spread)

typedef short bf16x8 __attribute__((ext_vector_type(8)));   // 8 bf16 = 4 VGPRs
typedef float f32x4  __attribute__((ext_vector_type(4)));

static __device__ inline unsigned short f32_to_bf16_rne(float f) {
    unsigned int u = __float_as_uint(f);
    u += 0x7FFFu + ((u >> 16) & 1u);   // round-nearest-even
    return (unsigned short)(u >> 16);
}
static __device__ inline float bf16_to_f32(unsigned short h) {
    return __uint_as_float(((unsigned int)h) << 16);
}

// Combined B fragments for mfma_f32_16x16x32_bf16 over extended K=256:
//   kk 0..3 -> W_seq rows, kk 4..7 -> W_last rows.
// ws[((kk*8+nt)*64+lane)*8+j] = W[(kk&3)*32+(lane>>4)*8+j][nt*16+(lane&15)]
__global__ void prep_w(const float* __restrict__ W_seq,
                       const float* __restrict__ W_last,
                       unsigned short* __restrict__ ws)
{
    int t = blockIdx.x * blockDim.x + threadIdx.x;   // 0..4095
    int lane = t & 63;
    int nt   = (t >> 6) & 7;
    int kk   = t >> 9;
    const float* W = (kk < 4) ? W_seq : W_last;
    int kb = (kk & 3) * 32 + (lane >> 4) * 8;
    int n  = nt * 16 + (lane & 15);
    unsigned short* dst = ws + (size_t)t * 8;
    #pragma unroll
    for (int j = 0; j < 8; ++j)
        dst[j] = f32_to_bf16_rne(W[(kb + j) * DD + n]);
}

// One independent wave per batch: 4096 blocks x 64 threads.
// No __syncthreads, no cross-wave atomics, all 64 lanes active in every phase.
// Wave-synchronous LDS: ds ops from one wave are ordered; compiler inserts lgkmcnt.
__global__ __launch_bounds__(64, 3) void sess_attn(
    const int*   __restrict__ seq_idx,   // [B,L]
    const int*   __restrict__ mask,      // [B,L]
    const float* __restrict__ nodes,     // [B,N,D]
    const float* __restrict__ b_seq,     // [D]
    const float* __restrict__ W_alpha,   // [D]
    const unsigned short* __restrict__ wfrag,  // d_ws, combined B-frags
    float*       __restrict__ out)       // [B*D] v_n, then [B*D] session_graph
{
    const int b    = blockIdx.x;
    const int lane = threadIdx.x;        // 0..63
    const int col  = lane & 15;
    const int quad = lane >> 4;

    __shared__ __align__(16) unsigned short s_t[NN * STR];  // 13600 B
    __shared__ float s_alpha[NN];
    __shared__ float s_cnt[NN];

    // ---- Issue ALL global loads up front (independent, all in flight). ----
    // 1) node tile: 1600 float4 over 64 lanes = 25 each (fully coalesced).
    const float4* nb4 = (const float4*)(nodes + (size_t)b * (NN * DD));
    float4 v[25];
    #pragma unroll
    for (int i = 0; i < 25; ++i) v[i] = nb4[lane + i * 64];

    // 2) mask/idx row.
    int pm = 0, pi = 0;
    if (lane < LL) {
        pm = mask[b * LL + lane];
        pi = seq_idx[b * LL + lane];
    }

    // 3) per-lane epilogue scalars for all 8 n-tiles.
    float bb[8], wa[8];
    #pragma unroll
    for (int j = 0; j < 8; ++j) {
        int n = j * 16 + col;
        bb[j] = b_seq[n];
        wa[j] = W_alpha[n];
    }

    if (lane < NN) s_cnt[lane] = 0.f;

    // ---- Convert + LDS-write the node tile (bf16). ----
    #pragma unroll
    for (int i = 0; i < 25; ++i) {
        int idx = lane + i * 64;
        int r = idx >> 5, c = (idx & 31) * 4;
        ushort4 h;
        h.x = f32_to_bf16_rne(v[i].x);
        h.y = f32_to_bf16_rne(v[i].y);
        h.z = f32_to_bf16_rne(v[i].z);
        h.w = f32_to_bf16_rne(v[i].w);
        *(ushort4*)&s_t[r * STR + c] = h;
    }

    // ---- seq_len, last index, count histogram (whole wave). ----
    int mm = pm;
    mm += __shfl_xor(mm, 1);  mm += __shfl_xor(mm, 2);
    mm += __shfl_xor(mm, 4);  mm += __shfl_xor(mm, 8);
    mm += __shfl_xor(mm, 16); mm += __shfl_xor(mm, 32);
    int jl = mm - 1;
    if (jl < 0) jl += LL;                 // JAX negative-index wrap
    const int last = __shfl(pi, jl);
    if (lane < LL && pm) atomicAdd(&s_cnt[pi], (float)pm);

    // v_n output: exact fp32 (row is L2-hot from the tile load).
    {
        const float2* vn2 = (const float2*)(nodes + (size_t)b * (NN * DD) + (size_t)last * DD);
        ((float2*)(out + (size_t)b * DD))[lane] = vn2[lane];
    }

    const bf16x8* wsf = (const bf16x8*)wfrag;

    // ---- Prepass: c[j] = (v_n @ W_last + b_seq) at col j*16+col.
    // All 16 A-rows are v_n (same LDS row), so C is row-invariant: keep 1 float/j.
    bf16x8 av[4];
    #pragma unroll
    for (int kk = 0; kk < 4; ++kk)
        av[kk] = *(const bf16x8*)&s_t[last * STR + kk * 32 + quad * 8];
    float c8[8];
    #pragma unroll
    for (int j = 0; j < 8; ++j) {
        f32x4 aV = (f32x4){bb[j], bb[j], bb[j], bb[j]};
        #pragma unroll
        for (int kk = 0; kk < 4; ++kk)
            aV = __builtin_amdgcn_mfma_f32_16x16x32_bf16(
                av[kk], wsf[(size_t)(((kk + 4) * 8 + j) * 64 + lane)], aV, 0, 0, 0);
        c8[j] = aV[0];
    }

    // ---- Main GEMM over all 8 n-tiles with fused sigmoid/W_alpha epilogue.
    // pr[m][r] accumulates this lane's column contribution across all tiles.
    float pr[4][4];
    #pragma unroll
    for (int m = 0; m < 4; ++m)
        #pragma unroll
        for (int r = 0; r < 4; ++r) pr[m][r] = 0.f;

    // A-tile rows; m=3 rows 50..63 are out of range -> clamp to 49 (discarded).
    const int ar0 = col, ar1 = 16 + col, ar2 = 32 + col;
    const int ar3 = (48 + col > NN - 1) ? (NN - 1) : (48 + col);

    #pragma unroll
    for (int j = 0; j < 8; ++j) {
        f32x4 acc[4];
        #pragma unroll
        for (int m = 0; m < 4; ++m) acc[m] = (f32x4){0.f, 0.f, 0.f, 0.f};
        #pragma unroll
        for (int kk = 0; kk < 4; ++kk) {
            bf16x8 bs = wsf[(size_t)((kk * 8 + j) * 64 + lane)];
            int co = kk * 32 + quad * 8;
            bf16x8 a0 = *(const bf16x8*)&s_t[ar0 * STR + co];
            bf16x8 a1 = *(const bf16x8*)&s_t[ar1 * STR + co];
            bf16x8 a2 = *(const bf16x8*)&s_t[ar2 * STR + co];
            bf16x8 a3 = *(const bf16x8*)&s_t[ar3 * STR + co];
            acc[0] = __builtin_amdgcn_mfma_f32_16x16x32_bf16(a0, bs, acc[0], 0, 0, 0);
            acc[1] = __builtin_amdgcn_mfma_f32_16x16x32_bf16(a1, bs, acc[1], 0, 0, 0);
            acc[2] = __builtin_amdgcn_mfma_f32_16x16x32_bf16(a2, bs, acc[2], 0, 0, 0);
            acc[3] = __builtin_amdgcn_mfma_f32_16x16x32_bf16(a3, bs, acc[3], 0, 0, 0);
        }
        float cj = c8[j], waj = wa[j];
        #pragma unroll
        for (int m = 0; m < 4; ++m)
            #pragma unroll
            for (int r = 0; r < 4; ++r) {
                float x = acc[m][r] + cj;
                float sig = 1.f / (1.f + __expf(-x));
                pr[m][r] = fmaf(sig, waj, pr[m][r]);
            }
    }

    // ---- Reduce over the 16 columns; one plain LDS store per row. ----
    // C layout: col = lane&15, row = m*16 + quad*4 + r.
    #pragma unroll
    for (int m = 0; m < 4; ++m) {
        #pragma unroll
        for (int r = 0; r < 4; ++r) {
            float vv = pr[m][r];
            vv += __shfl_xor(vv, 1);
            vv += __shfl_xor(vv, 2);
            vv += __shfl_xor(vv, 4);
            vv += __shfl_xor(vv, 8);
            int row = m * 16 + quad * 4 + r;
            if (col == 0 && row < NN) s_alpha[row] = vv;
        }
    }

    // ---- Fold counts into alpha, then weighted sum over nodes. ----
    if (lane < NN) s_alpha[lane] *= s_cnt[lane];   // wn = cnt*alpha (wave-ordered)

    float a0 = 0.f, a1 = 0.f;
    const int d0 = lane * 2;
    #pragma unroll 10
    for (int n = 0; n < NN; ++n) {
        float wn = s_alpha[n];                     // broadcast read
        unsigned int tv = *(const unsigned int*)&s_t[n * STR + d0];  // 2 bf16
        a0 = fmaf(wn, bf16_to_f32((unsigned short)(tv & 0xFFFFu)), a0);
        a1 = fmaf(wn, bf16_to_f32((unsigned short)(tv >> 16)), a1);
    }
    float2 o; o.x = a0; o.y = a1;
    ((float2*)(out + (size_t)BB * DD + (size_t)b * DD))[lane] = o;
}

extern "C" void kernel_launch(void* const* d_in, const int* in_sizes, int n_in,
                              void* d_out, int out_size, void* d_ws, size_t ws_size,
                              hipStream_t stream) {
    const int*   seq     = (const int*)  d_in[0];
    const int*   mask    = (const int*)  d_in[1];
    const float* nodes   = (const float*)d_in[2];
    // d_in[3] = batch_size scalar (shapes compile-time fixed)
    const float* W_last  = (const float*)d_in[4];
    const float* W_seq   = (const float*)d_in[5];
    const float* b_seq   = (const float*)d_in[6];
    const float* W_alpha = (const float*)d_in[7];
    float*       out     = (float*)      d_out;

    unsigned short* wsf = (unsigned short*)d_ws;   // 64 KB combined B-fragments

    prep_w<<<16, 256, 0, stream>>>(W_seq, W_last, wsf);
    sess_attn<<<BB, 64, 0, stream>>>(seq, mask, nodes, b_seq, W_alpha, wsf, out);
}

// Round 2
// 202.718 us; speedup vs baseline: 1.1471x; 1.1471x over previous
//
#include <hip/hip_runtime.h>
#include <math.h>

#define BB 4096
#define LL 50
#define NN 50
#define DD 128

typedef short bf16x8 __attribute__((ext_vector_type(8)));   // 8 bf16 = 4 VGPRs
typedef float f32x4  __attribute__((ext_vector_type(4)));

static __device__ inline unsigned short f32_to_bf16_rne(float f) {
    unsigned int u = __float_as_uint(f);
    u += 0x7FFFu + ((u >> 16) & 1u);   // round-nearest-even
    return (unsigned short)(u >> 16);
}

static __device__ inline bf16x8 pack8(float4 lo, float4 hi) {
    bf16x8 r;
    r[0] = (short)f32_to_bf16_rne(lo.x);
    r[1] = (short)f32_to_bf16_rne(lo.y);
    r[2] = (short)f32_to_bf16_rne(lo.z);
    r[3] = (short)f32_to_bf16_rne(lo.w);
    r[4] = (short)f32_to_bf16_rne(hi.x);
    r[5] = (short)f32_to_bf16_rne(hi.y);
    r[6] = (short)f32_to_bf16_rne(hi.z);
    r[7] = (short)f32_to_bf16_rne(hi.w);
    return r;
}

// Combined B fragments for mfma_f32_16x16x32_bf16 over extended K=256:
//   kk 0..3 -> W_seq rows, kk 4..7 -> W_last rows.
// ws[((kk*8+nt)*64+lane)*8+j] = W[(kk&3)*32+(lane>>4)*8+j][nt*16+(lane&15)]
__global__ void prep_w(const float* __restrict__ W_seq,
                       const float* __restrict__ W_last,
                       unsigned short* __restrict__ ws)
{
    int t = blockIdx.x * blockDim.x + threadIdx.x;   // 0..4095
    int lane = t & 63;
    int nt   = (t >> 6) & 7;
    int kk   = t >> 9;
    const float* W = (kk < 4) ? W_seq : W_last;
    int kb = (kk & 3) * 32 + (lane >> 4) * 8;
    int n  = nt * 16 + (lane & 15);
    unsigned short* dst = ws + (size_t)t * 8;
    #pragma unroll
    for (int j = 0; j < 8; ++j)
        dst[j] = f32_to_bf16_rne(W[(kb + j) * DD + n]);
}

// One independent wave per batch: 4096 blocks x 64 threads, no barriers.
// Node tile staged as LINEAR f32 [50][128] via global_load_lds (zero VGPR,
// spill-proof). 16B blocks XOR-swizzled on the GLOBAL source address
// (blk ^= row&7); every LDS read applies the same XOR -> column-slice
// fragment reads are 2-way (free) instead of 16-way conflicted.
__global__ __launch_bounds__(64) void sess_attn(
    const int*   __restrict__ seq_idx,   // [B,L]
    const int*   __restrict__ mask,      // [B,L]
    const float* __restrict__ nodes,     // [B,N,D]
    const float* __restrict__ b_seq,     // [D]
    const float* __restrict__ W_alpha,   // [D]
    const unsigned short* __restrict__ wfrag,  // d_ws, combined B-frags
    float*       __restrict__ out)       // [B*D] v_n, then [B*D] session_graph
{
    const int b    = blockIdx.x;
    const int lane = threadIdx.x;        // 0..63
    const int col  = lane & 15;
    const int quad = lane >> 4;

    __shared__ __align__(16) float s_f[NN * DD];   // 25600 B, LINEAR (DMA dest)
    __shared__ float s_cnt[64];
    __shared__ float s_w[64];

    const float* nb = nodes + (size_t)b * (NN * DD);

    // ---- 1) mask/idx first (oldest vmcnt slots -> shuffle phase waits
    //         only on these, not on the tile DMA). ----
    int pm = 0, pi = 0;
    if (lane < LL) {
        pm = mask[b * LL + lane];
        pi = seq_idx[b * LL + lane];
    }
    s_cnt[lane] = 0.f;

    // ---- 2) issue the whole tile as 25 global_load_lds (1 KB each). ----
    #pragma unroll
    for (int i = 0; i < 25; ++i) {
        int p  = i * 64 + lane;            // 16B-block index 0..1599
        int r  = p >> 5;                   // node row 0..49
        int Bk = p & 31;                   // block within row
        const float* src = nb + r * DD + ((Bk ^ (r & 7)) << 2);  // pre-swizzled
        __builtin_amdgcn_global_load_lds(
            (const __attribute__((address_space(1))) unsigned int*)src,
            (__attribute__((address_space(3))) unsigned int*)(&s_f[i * 256]),
            16, 0, 0);
    }

    // ---- 3) epilogue scalars (L2-hot). ----
    float bb_[8], wa[8];
    #pragma unroll
    for (int j = 0; j < 8; ++j) {
        int n = j * 16 + col;
        bb_[j] = b_seq[n];
        wa[j]  = W_alpha[n];
    }

    // ---- 4) seq_len, last index, count histogram (overlaps tile DMA). ----
    int mm = pm;
    mm += __shfl_xor(mm, 1);  mm += __shfl_xor(mm, 2);
    mm += __shfl_xor(mm, 4);  mm += __shfl_xor(mm, 8);
    mm += __shfl_xor(mm, 16); mm += __shfl_xor(mm, 32);
    int jl = mm - 1;
    if (jl < 0) jl += LL;                 // JAX negative-index wrap
    const int last = __shfl(pi, jl);
    if (lane < LL && pm) atomicAdd(&s_cnt[pi], (float)pm);

    // ---- 5) drain the DMA; tile now valid in LDS. ----
    asm volatile("s_waitcnt vmcnt(0)" ::: "memory");

    const int sL = last & 7;

    // v_n output: exact f32 straight from LDS.
    {
        int Bk = lane >> 1;
        float2 vv = *(const float2*)&s_f[last * DD + ((Bk ^ sL) << 2) + ((lane & 1) << 1)];
        ((float2*)(out + (size_t)b * DD))[lane] = vv;
    }

    // ---- 6) build all A-fragments once (reused across all 8 n-tiles). ----
    // fr[kk][m]: lane holds A[row = m*16+col][k = kk*32+quad*8 .. +7].
    const int ar[4] = { col, 16 + col, 32 + col,
                        (48 + col > NN - 1) ? (NN - 1) : (48 + col) };
    bf16x8 fr[4][4];
    #pragma unroll
    for (int kk = 0; kk < 4; ++kk) {
        int B1 = kk * 8 + quad * 2;
        #pragma unroll
        for (int m = 0; m < 4; ++m) {
            int r = ar[m], s = r & 7;
            float4 lo = *(const float4*)&s_f[r * DD + ((B1 ^ s) << 2)];
            float4 hi = *(const float4*)&s_f[r * DD + (((B1 + 1) ^ s) << 2)];
            fr[kk][m] = pack8(lo, hi);
        }
    }

    // ---- 7) prepass: c8[j] = (v_n @ W_last + b_seq)[j*16+col].
    // All A-rows = v_n (broadcast LDS reads) -> C row-invariant, keep acc[0].
    const bf16x8* wsf = (const bf16x8*)wfrag;
    float c8[8];
    {
        bf16x8 av[4];
        #pragma unroll
        for (int kk = 0; kk < 4; ++kk) {
            int B1 = kk * 8 + quad * 2;
            float4 lo = *(const float4*)&s_f[last * DD + ((B1 ^ sL) << 2)];
            float4 hi = *(const float4*)&s_f[last * DD + (((B1 + 1) ^ sL) << 2)];
            av[kk] = pack8(lo, hi);
        }
        #pragma unroll
        for (int j = 0; j < 8; ++j) {
            f32x4 aV = (f32x4){bb_[j], bb_[j], bb_[j], bb_[j]};
            #pragma unroll
            for (int kk = 0; kk < 4; ++kk)
                aV = __builtin_amdgcn_mfma_f32_16x16x32_bf16(
                    av[kk], wsf[(size_t)(((kk + 4) * 8 + j) * 64 + lane)], aV, 0, 0, 0);
            c8[j] = aV[0];
        }
    }

    // ---- 8) main GEMM: 8 n-tiles x 4 k-steps, fused sigmoid epilogue. ----
    float pr[4][4];
    #pragma unroll
    for (int m = 0; m < 4; ++m)
        #pragma unroll
        for (int r = 0; r < 4; ++r) pr[m][r] = 0.f;

    #pragma unroll
    for (int j = 0; j < 8; ++j) {
        f32x4 acc[4];
        #pragma unroll
        for (int m = 0; m < 4; ++m) acc[m] = (f32x4){0.f, 0.f, 0.f, 0.f};
        #pragma unroll
        for (int kk = 0; kk < 4; ++kk) {
            bf16x8 bs = wsf[(size_t)((kk * 8 + j) * 64 + lane)];
            acc[0] = __builtin_amdgcn_mfma_f32_16x16x32_bf16(fr[kk][0], bs, acc[0], 0, 0, 0);
            acc[1] = __builtin_amdgcn_mfma_f32_16x16x32_bf16(fr[kk][1], bs, acc[1], 0, 0, 0);
            acc[2] = __builtin_amdgcn_mfma_f32_16x16x32_bf16(fr[kk][2], bs, acc[2], 0, 0, 0);
            acc[3] = __builtin_amdgcn_mfma_f32_16x16x32_bf16(fr[kk][3], bs, acc[3], 0, 0, 0);
        }
        float cj = c8[j], waj = wa[j];
        #pragma unroll
        for (int m = 0; m < 4; ++m)
            #pragma unroll
            for (int r = 0; r < 4; ++r) {
                float x = acc[m][r] + cj;
                float sig = 1.f / (1.f + __expf(-x));
                pr[m][r] = fmaf(sig, waj, pr[m][r]);
            }
    }

    // ---- 9) reduce over the 16 columns; plain LDS store per row. ----
    // C layout: col = lane&15, row = m*16 + quad*4 + r.
    #pragma unroll
    for (int m = 0; m < 4; ++m) {
        #pragma unroll
        for (int r = 0; r < 4; ++r) {
            float vv = pr[m][r];
            vv += __shfl_xor(vv, 1);
            vv += __shfl_xor(vv, 2);
            vv += __shfl_xor(vv, 4);
            vv += __shfl_xor(vv, 8);
            int row = m * 16 + quad * 4 + r;
            if (col == 0 && row < NN) s_w[row] = vv;
        }
    }

    // fold counts (wave-synchronous LDS ordering, same pattern as before).
    if (lane < NN) s_w[lane] *= s_cnt[lane];

    // ---- 10) session_graph[d] = sum_n w[n] * nodes_f32[n][d]. ----
    float a0 = 0.f, a1 = 0.f;
    const int Bk  = lane >> 1;
    const int off = (lane & 1) << 1;
    #pragma unroll 10
    for (int n = 0; n < NN; ++n) {
        float wn = s_w[n];                                   // broadcast
        float2 tv = *(const float2*)&s_f[n * DD + ((Bk ^ (n & 7)) << 2) + off];
        a0 = fmaf(wn, tv.x, a0);
        a1 = fmaf(wn, tv.y, a1);
    }
    float2 o; o.x = a0; o.y = a1;
    ((float2*)(out + (size_t)BB * DD + (size_t)b * DD))[lane] = o;
}

extern "C" void kernel_launch(void* const* d_in, const int* in_sizes, int n_in,
                              void* d_out, int out_size, void* d_ws, size_t ws_size,
                              hipStream_t stream) {
    const int*   seq     = (const int*)  d_in[0];
    const int*   mask    = (const int*)  d_in[1];
    const float* nodes   = (const float*)d_in[2];
    // d_in[3] = batch_size scalar (shapes compile-time fixed)
    const float* W_last  = (const float*)d_in[4];
    const float* W_seq   = (const float*)d_in[5];
    const float* b_seq   = (const float*)d_in[6];
    const float* W_alpha = (const float*)d_in[7];
    float*       out     = (float*)      d_out;

    unsigned short* wsf = (unsigned short*)d_ws;   // 64 KB combined B-fragments

    prep_w<<<16, 256, 0, stream>>>(W_seq, W_last, wsf);
    sess_attn<<<BB, 64, 0, stream>>>(seq, mask, nodes, b_seq, W_alpha, wsf, out);
}

// Round 4
// 191.328 us; speedup vs baseline: 1.2154x; 1.0595x over previous
//
#include <hip/hip_runtime.h>
#include <math.h>

#define BB 4096
#define LL 50
#define NN 50
#define DD 128

typedef short bf16x8 __attribute__((ext_vector_type(8)));   // 8 bf16 = 4 VGPRs
typedef float f32x4  __attribute__((ext_vector_type(4)));

static __device__ inline unsigned short f32_to_bf16_rne(float f) {
    unsigned int u = __float_as_uint(f);
    u += 0x7FFFu + ((u >> 16) & 1u);   // round-nearest-even
    return (unsigned short)(u >> 16);
}

static __device__ inline bf16x8 pack8(float4 lo, float4 hi) {
    bf16x8 r;
    r[0] = (short)f32_to_bf16_rne(lo.x);
    r[1] = (short)f32_to_bf16_rne(lo.y);
    r[2] = (short)f32_to_bf16_rne(lo.z);
    r[3] = (short)f32_to_bf16_rne(lo.w);
    r[4] = (short)f32_to_bf16_rne(hi.x);
    r[5] = (short)f32_to_bf16_rne(hi.y);
    r[6] = (short)f32_to_bf16_rne(hi.z);
    r[7] = (short)f32_to_bf16_rne(hi.w);
    return r;
}

// Combined B fragments for mfma_f32_16x16x32_bf16 over extended K=256:
//   kk 0..3 -> W_seq rows, kk 4..7 -> W_last rows.
// ws[((kk*8+nt)*64+lane)*8+j] = W[(kk&3)*32+(lane>>4)*8+j][nt*16+(lane&15)]
__global__ void prep_w(const float* __restrict__ W_seq,
                       const float* __restrict__ W_last,
                       unsigned short* __restrict__ ws)
{
    int t = blockIdx.x * blockDim.x + threadIdx.x;   // 0..4095
    int lane = t & 63;
    int nt   = (t >> 6) & 7;
    int kk   = t >> 9;
    const float* W = (kk < 4) ? W_seq : W_last;
    int kb = (kk & 3) * 32 + (lane >> 4) * 8;
    int n  = nt * 16 + (lane & 15);
    unsigned short* dst = ws + (size_t)t * 8;
    #pragma unroll
    for (int j = 0; j < 8; ++j)
        dst[j] = f32_to_bf16_rne(W[(kb + j) * DD + n]);
}

// 4096 blocks x 256 threads (4 waves). Wave w owns n-tiles {2w, 2w+1}, all
// m-tiles -> only 16 B-fragments per wave (preloadable). Node tile staged as
// LINEAR f32 [50][128] via global_load_lds (zero VGPR, spill-proof).
// CRITICAL (m104/m108): global_load_lds LDS dest is WAVE-UNIFORM base +
// lane*16; per-wave uniform bases below, per-lane swizzle carried entirely
// on the GLOBAL source address (blk ^= row&7). Every LDS read applies the
// same XOR -> column-slice fragment reads conflict-free.
__global__ __launch_bounds__(256, 4) void sess_attn(
    const int*   __restrict__ seq_idx,   // [B,L]
    const int*   __restrict__ mask,      // [B,L]
    const float* __restrict__ nodes,     // [B,N,D]
    const float* __restrict__ b_seq,     // [D]
    const float* __restrict__ W_alpha,   // [D]
    const unsigned short* __restrict__ wfrag,  // d_ws, combined B-frags
    float*       __restrict__ out)       // [B*D] v_n, then [B*D] session_graph
{
    const int b    = blockIdx.x;
    const int tid  = threadIdx.x;
    const int lane = tid & 63;
    const int wave = tid >> 6;
    const int col  = lane & 15;
    const int quad = lane >> 4;

    __shared__ __align__(16) float s_f[NN * DD];   // 25600 B, LINEAR (DMA dest)
    __shared__ float s_alpha[64];
    __shared__ float s_cnt[64];
    __shared__ int   s_last;

    const float* nb = nodes + (size_t)b * (NN * DD);

    // ---- 1) mask/idx first (wave 0 consumes them before the DMA drains). ----
    int pm = 0, pi = 0;
    if (tid < 64) {
        pm = (tid < LL) ? mask[b * LL + tid]    : 0;
        pi = (tid < LL) ? seq_idx[b * LL + tid] : 0;
    }

    // ---- 2) whole tile: 25 x 1KB global_load_lds, wave-uniform LDS bases. ----
    #pragma unroll
    for (int i = 0; i < 6; ++i) {
        int p  = i * 256 + tid;            // 16B-block index = base_blk + lane
        int r  = p >> 5;                   // node row
        int Bk = p & 31;                   // block within row
        const float* src = nb + r * DD + ((Bk ^ (r & 7)) << 2);  // pre-swizzled
        __builtin_amdgcn_global_load_lds(
            (const __attribute__((address_space(1))) unsigned int*)src,
            (__attribute__((address_space(3))) unsigned int*)(&s_f[(i * 256 + wave * 64) * 4]),
            16, 0, 0);                     // lane l lands at base + l*16B
    }
    if (tid < 64) {                        // wave 0 tail: blocks 1536..1599
        int p  = 1536 + tid;
        int r  = p >> 5, Bk = p & 31;
        const float* src = nb + r * DD + ((Bk ^ (r & 7)) << 2);
        __builtin_amdgcn_global_load_lds(
            (const __attribute__((address_space(1))) unsigned int*)src,
            (__attribute__((address_space(3))) unsigned int*)(&s_f[1536 * 4]),
            16, 0, 0);
    }

    // ---- 3) this wave's W_seq fragments (L2-resident table) + scalars. ----
    const bf16x8* wsf = (const bf16x8*)wfrag;
    bf16x8 bfS[8];
    #pragma unroll
    for (int kk = 0; kk < 4; ++kk)
        #pragma unroll
        for (int j2 = 0; j2 < 2; ++j2)
            bfS[kk * 2 + j2] = wsf[(size_t)((kk * 8 + wave * 2 + j2) * 64 + lane)];

    float bb_r[2], wa_r[2];
    #pragma unroll
    for (int j2 = 0; j2 < 2; ++j2) {
        int n = (wave * 2 + j2) * 16 + col;
        bb_r[j2] = b_seq[n];
        wa_r[j2] = W_alpha[n];
    }

    // ---- 4) wave 0: zero accum slots, seq_len, last index, histogram. ----
    if (tid < 64) {
        s_alpha[tid] = 0.f;
        s_cnt[tid]   = 0.f;
        int mm = pm;
        mm += __shfl_xor(mm, 1);  mm += __shfl_xor(mm, 2);
        mm += __shfl_xor(mm, 4);  mm += __shfl_xor(mm, 8);
        mm += __shfl_xor(mm, 16); mm += __shfl_xor(mm, 32);
        int jl = mm - 1;
        if (jl < 0) jl += LL;                 // JAX negative-index wrap
        int li = __shfl(pi, jl);              // uniform shuffle, then branch
        if (tid == 0) s_last = li;
        if (tid < LL && pm) atomicAdd(&s_cnt[pi], (float)pm);
    }

    __syncthreads();   // drains each wave's DMA (vmcnt 0) + barrier

    const int last = s_last;
    const int sL   = last & 7;

    // v_n output: exact f32 straight from LDS (un-swizzle via same XOR).
    if (tid < DD)
        out[(size_t)b * DD + tid] =
            s_f[last * DD + (((tid >> 2) ^ sL) << 2) + (tid & 3)];

    // ---- 5) MFMA: acc (W_seq) per m-tile; accV (W_last) row-invariant. ----
    f32x4 acc[4][2];
    #pragma unroll
    for (int m = 0; m < 4; ++m)
        #pragma unroll
        for (int j2 = 0; j2 < 2; ++j2)
            acc[m][j2] = (f32x4){0.f, 0.f, 0.f, 0.f};
    f32x4 accV[2];
    #pragma unroll
    for (int j2 = 0; j2 < 2; ++j2)
        accV[j2] = (f32x4){bb_r[j2], bb_r[j2], bb_r[j2], bb_r[j2]};

    #pragma unroll
    for (int kk = 0; kk < 4; ++kk) {
        const int B1 = kk * 8 + quad * 2;
        bf16x8 a[4];
        #pragma unroll
        for (int m = 0; m < 4; ++m) {
            int r = m * 16 + col;
            if (r > NN - 1) r = NN - 1;       // m=3 tail rows discarded later
            int s = r & 7;
            float4 lo = *(const float4*)&s_f[r * DD + ((B1 ^ s) << 2)];
            float4 hi = *(const float4*)&s_f[r * DD + (((B1 + 1) ^ s) << 2)];
            a[m] = pack8(lo, hi);
        }
        float4 vlo = *(const float4*)&s_f[last * DD + ((B1 ^ sL) << 2)];
        float4 vhi = *(const float4*)&s_f[last * DD + (((B1 + 1) ^ sL) << 2)];
        bf16x8 av = pack8(vlo, vhi);
        #pragma unroll
        for (int j2 = 0; j2 < 2; ++j2) {
            bf16x8 bl = wsf[(size_t)(((kk + 4) * 8 + wave * 2 + j2) * 64 + lane)];
            acc[0][j2] = __builtin_amdgcn_mfma_f32_16x16x32_bf16(a[0], bfS[kk * 2 + j2], acc[0][j2], 0, 0, 0);
            acc[1][j2] = __builtin_amdgcn_mfma_f32_16x16x32_bf16(a[1], bfS[kk * 2 + j2], acc[1][j2], 0, 0, 0);
            acc[2][j2] = __builtin_amdgcn_mfma_f32_16x16x32_bf16(a[2], bfS[kk * 2 + j2], acc[2][j2], 0, 0, 0);
            acc[3][j2] = __builtin_amdgcn_mfma_f32_16x16x32_bf16(a[3], bfS[kk * 2 + j2], acc[3][j2], 0, 0, 0);
            accV[j2]   = __builtin_amdgcn_mfma_f32_16x16x32_bf16(av,   bl,              accV[j2],   0, 0, 0);
        }
    }

    // ---- 6) epilogue: alpha[row] += sum_cols sigmoid(acc+accV)*W_alpha. ----
    // C layout: col = lane&15, row = m*16 + quad*4 + r.
    #pragma unroll
    for (int m = 0; m < 4; ++m) {
        float pr[4] = {0.f, 0.f, 0.f, 0.f};
        #pragma unroll
        for (int j2 = 0; j2 < 2; ++j2) {
            float waj = wa_r[j2];
            #pragma unroll
            for (int r = 0; r < 4; ++r) {
                float x = acc[m][j2][r] + accV[j2][r];
                float sig = 1.f / (1.f + __expf(-x));
                pr[r] = fmaf(sig, waj, pr[r]);
            }
        }
        #pragma unroll
        for (int r = 0; r < 4; ++r) {
            float vv = pr[r];
            vv += __shfl_xor(vv, 1);
            vv += __shfl_xor(vv, 2);
            vv += __shfl_xor(vv, 4);
            vv += __shfl_xor(vv, 8);
            int row = m * 16 + quad * 4 + r;
            if (col == 0 && row < NN) atomicAdd(&s_alpha[row], vv);
        }
    }
    __syncthreads();   // s_alpha complete

    // ---- 7) session_graph[d] = sum_n cnt[n]*alpha[n]*nodes_f32[n][d]. ----
    if (tid < DD) {
        const int Bd = tid >> 2, od = tid & 3;
        float acc2 = 0.f;
        #pragma unroll 10
        for (int n = 0; n < NN; ++n)
            acc2 = fmaf(s_cnt[n] * s_alpha[n],
                        s_f[n * DD + ((Bd ^ (n & 7)) << 2) + od], acc2);
        out[(size_t)BB * DD + (size_t)b * DD + tid] = acc2;
    }
}

extern "C" void kernel_launch(void* const* d_in, const int* in_sizes, int n_in,
                              void* d_out, int out_size, void* d_ws, size_t ws_size,
                              hipStream_t stream) {
    const int*   seq     = (const int*)  d_in[0];
    const int*   mask    = (const int*)  d_in[1];
    const float* nodes   = (const float*)d_in[2];
    // d_in[3] = batch_size scalar (shapes compile-time fixed)
    const float* W_last  = (const float*)d_in[4];
    const float* W_seq   = (const float*)d_in[5];
    const float* b_seq   = (const float*)d_in[6];
    const float* W_alpha = (const float*)d_in[7];
    float*       out     = (float*)      d_out;

    unsigned short* wsf = (unsigned short*)d_ws;   // 64 KB combined B-fragments

    prep_w<<<16, 256, 0, stream>>>(W_seq, W_last, wsf);
    sess_attn<<<BB, 256, 0, stream>>>(seq, mask, nodes, b_seq, W_alpha, wsf, out);
}

// Round 5
// 179.218 us; speedup vs baseline: 1.2975x; 1.0676x over previous
//
#include <hip/hip_runtime.h>
#include <math.h>

#define BB 4096
#define LL 50
#define NN 50
#define DD 128
#define STR 136    // bf16 LDS row stride in shorts (272 B: odd 4-bank rotation/row)

typedef short bf16x8 __attribute__((ext_vector_type(8)));   // 8 bf16 = 4 VGPRs
typedef float f32x4  __attribute__((ext_vector_type(4)));

static __device__ inline unsigned short f32_to_bf16_rne(float f) {
    unsigned int u = __float_as_uint(f);
    u += 0x7FFFu + ((u >> 16) & 1u);   // round-nearest-even
    return (unsigned short)(u >> 16);
}

// Combined B fragments for mfma_f32_16x16x32_bf16 over extended K=256:
//   kk 0..3 -> W_seq rows, kk 4..7 -> W_last rows.
// ws[((kk*8+nt)*64+lane)*8+j] = W[(kk&3)*32+(lane>>4)*8+j][nt*16+(lane&15)]
__global__ void prep_w(const float* __restrict__ W_seq,
                       const float* __restrict__ W_last,
                       unsigned short* __restrict__ ws)
{
    int t = blockIdx.x * blockDim.x + threadIdx.x;   // 0..4095
    int lane = t & 63;
    int nt   = (t >> 6) & 7;
    int kk   = t >> 9;
    const float* W = (kk < 4) ? W_seq : W_last;
    int kb = (kk & 3) * 32 + (lane >> 4) * 8;
    int n  = nt * 16 + (lane & 15);
    unsigned short* dst = ws + (size_t)t * 8;
    #pragma unroll
    for (int j = 0; j < 8; ++j)
        dst[j] = f32_to_bf16_rne(W[(kb + j) * DD + n]);
}

// 4096 blocks x 256 threads (4 waves). Wave w owns n-tiles {2w, 2w+1}.
// Staging: global_load_lds f32 (wave-uniform LDS base + lane*16 — m104/m108),
// per-lane XOR (blk ^= row&7) carried on the GLOBAL source address. Then each
// wave converts exactly the blocks IT loaded (own vmcnt(0), no barrier) into
// a bf16 tile at STR=136, un-XOR-ing during the write. MFMA phase reads bf16
// fragments with single ds_read_b128 each — zero repack VALU (round 4 spent
// ~1600 VALU wave-inst/block on 6.4x-redundant per-wave f32->bf16 repacks).
__global__ __launch_bounds__(256, 4) void sess_attn(
    const int*   __restrict__ seq_idx,   // [B,L]
    const int*   __restrict__ mask,      // [B,L]
    const float* __restrict__ nodes,     // [B,N,D]
    const float* __restrict__ b_seq,     // [D]
    const float* __restrict__ W_alpha,   // [D]
    const unsigned short* __restrict__ wfrag,  // d_ws, combined B-frags
    float*       __restrict__ out)       // [B*D] v_n, then [B*D] session_graph
{
    const int b    = blockIdx.x;
    const int tid  = threadIdx.x;
    const int lane = tid & 63;
    const int wave = tid >> 6;
    const int col  = lane & 15;
    const int quad = lane >> 4;

    __shared__ __align__(16) float s_f[NN * DD];            // 25600 B (DMA dest)
    __shared__ __align__(16) unsigned short s_nbf[NN * STR]; // 13600 B bf16 tile
    __shared__ float s_alpha[64];
    __shared__ float s_cnt[64];
    __shared__ int   s_last;

    const float* nb = nodes + (size_t)b * (NN * DD);

    // ---- 1) mask/idx first. ----
    int pm = 0, pi = 0;
    if (tid < 64) {
        pm = (tid < LL) ? mask[b * LL + tid]    : 0;
        pi = (tid < LL) ? seq_idx[b * LL + tid] : 0;
    }

    // ---- 2) whole tile: 25 x 1KB global_load_lds, wave-uniform LDS bases. ----
    #pragma unroll
    for (int i = 0; i < 6; ++i) {
        int p  = i * 256 + tid;            // 16B-block index = base_blk + lane
        int r  = p >> 5;                   // node row
        int Bk = p & 31;                   // block within row
        const float* src = nb + r * DD + ((Bk ^ (r & 7)) << 2);  // pre-swizzled
        __builtin_amdgcn_global_load_lds(
            (const __attribute__((address_space(1))) unsigned int*)src,
            (__attribute__((address_space(3))) unsigned int*)(&s_f[(i * 256 + wave * 64) * 4]),
            16, 0, 0);                     // lane l lands at base + l*16B
    }
    if (tid < 64) {                        // wave 0 tail: blocks 1536..1599
        int p  = 1536 + tid;
        int r  = p >> 5, Bk = p & 31;
        const float* src = nb + r * DD + ((Bk ^ (r & 7)) << 2);
        __builtin_amdgcn_global_load_lds(
            (const __attribute__((address_space(1))) unsigned int*)src,
            (__attribute__((address_space(3))) unsigned int*)(&s_f[1536 * 4]),
            16, 0, 0);
    }

    // ---- 3) this wave's B-fragments (L2-resident) + epilogue scalars. ----
    const bf16x8* wsf = (const bf16x8*)wfrag;
    bf16x8 bfS[8], bfL[8];
    #pragma unroll
    for (int kk = 0; kk < 4; ++kk)
        #pragma unroll
        for (int j2 = 0; j2 < 2; ++j2) {
            bfS[kk * 2 + j2] = wsf[(size_t)(((kk    ) * 8 + wave * 2 + j2) * 64 + lane)];
            bfL[kk * 2 + j2] = wsf[(size_t)(((kk + 4) * 8 + wave * 2 + j2) * 64 + lane)];
        }

    float bb_r[2], wa_r[2];
    #pragma unroll
    for (int j2 = 0; j2 < 2; ++j2) {
        int n = (wave * 2 + j2) * 16 + col;
        bb_r[j2] = b_seq[n];
        wa_r[j2] = W_alpha[n];
    }

    if (tid < 64) { s_alpha[tid] = 0.f; s_cnt[tid] = 0.f; }

    // ---- 4) drain own DMA; convert exactly the blocks THIS wave loaded
    //         (wave-synchronous; overlaps other waves' DMA). ----
    asm volatile("s_waitcnt vmcnt(0)" ::: "memory");
    #pragma unroll
    for (int i = 0; i < 6; ++i) {
        int p  = i * 256 + wave * 64 + lane;
        int r  = p >> 5, Bk = p & 31;
        float4 f = *(const float4*)&s_f[p * 4];
        ushort4 h;
        h.x = f32_to_bf16_rne(f.x);
        h.y = f32_to_bf16_rne(f.y);
        h.z = f32_to_bf16_rne(f.z);
        h.w = f32_to_bf16_rne(f.w);
        *(ushort4*)&s_nbf[r * STR + ((Bk ^ (r & 7)) << 2)] = h;   // un-XOR
    }
    if (tid < 64) {
        int p  = 1536 + lane;
        int r  = p >> 5, Bk = p & 31;
        float4 f = *(const float4*)&s_f[p * 4];
        ushort4 h;
        h.x = f32_to_bf16_rne(f.x);
        h.y = f32_to_bf16_rne(f.y);
        h.z = f32_to_bf16_rne(f.z);
        h.w = f32_to_bf16_rne(f.w);
        *(ushort4*)&s_nbf[r * STR + ((Bk ^ (r & 7)) << 2)] = h;
    }

    // ---- 5) wave 0: seq_len, last index, histogram. ----
    if (tid < 64) {
        int mm = pm;
        mm += __shfl_xor(mm, 1);  mm += __shfl_xor(mm, 2);
        mm += __shfl_xor(mm, 4);  mm += __shfl_xor(mm, 8);
        mm += __shfl_xor(mm, 16); mm += __shfl_xor(mm, 32);
        int jl = mm - 1;
        if (jl < 0) jl += LL;                 // JAX negative-index wrap
        int li = __shfl(pi, jl);
        if (tid == 0) s_last = li;
        if (tid < LL && pm) atomicAdd(&s_cnt[pi], (float)pm);
    }

    __syncthreads();   // bf16 tile + s_last + s_cnt + s_alpha init visible

    const int last = s_last;
    const int sL   = last & 7;

    // v_n output: exact f32 from the staged tile (un-swizzle via same XOR).
    if (tid < DD)
        out[(size_t)b * DD + tid] =
            s_f[last * DD + (((tid >> 2) ^ sL) << 2) + (tid & 3)];

    // ---- 6) MFMA: acc (W_seq) per m-tile; accV (W_last) row-invariant. ----
    f32x4 acc[4][2];
    #pragma unroll
    for (int m = 0; m < 4; ++m)
        #pragma unroll
        for (int j2 = 0; j2 < 2; ++j2)
            acc[m][j2] = (f32x4){0.f, 0.f, 0.f, 0.f};
    f32x4 accV[2];
    #pragma unroll
    for (int j2 = 0; j2 < 2; ++j2)
        accV[j2] = (f32x4){bb_r[j2], bb_r[j2], bb_r[j2], bb_r[j2]};

    #pragma unroll
    for (int kk = 0; kk < 4; ++kk) {
        const int co = kk * 32 + quad * 8;
        bf16x8 a[4];
        #pragma unroll
        for (int m = 0; m < 4; ++m) {
            int r = m * 16 + col;
            if (r > NN - 1) r = NN - 1;       // m=3 tail rows discarded later
            a[m] = *(const bf16x8*)&s_nbf[r * STR + co];
        }
        bf16x8 av = *(const bf16x8*)&s_nbf[last * STR + co];
        #pragma unroll
        for (int j2 = 0; j2 < 2; ++j2) {
            acc[0][j2] = __builtin_amdgcn_mfma_f32_16x16x32_bf16(a[0], bfS[kk * 2 + j2], acc[0][j2], 0, 0, 0);
            acc[1][j2] = __builtin_amdgcn_mfma_f32_16x16x32_bf16(a[1], bfS[kk * 2 + j2], acc[1][j2], 0, 0, 0);
            acc[2][j2] = __builtin_amdgcn_mfma_f32_16x16x32_bf16(a[2], bfS[kk * 2 + j2], acc[2][j2], 0, 0, 0);
            acc[3][j2] = __builtin_amdgcn_mfma_f32_16x16x32_bf16(a[3], bfS[kk * 2 + j2], acc[3][j2], 0, 0, 0);
            accV[j2]   = __builtin_amdgcn_mfma_f32_16x16x32_bf16(av,   bfL[kk * 2 + j2], accV[j2],   0, 0, 0);
        }
    }

    // ---- 7) epilogue: alpha[row] += sum_cols sigmoid(acc+accV)*W_alpha. ----
    // C layout: col = lane&15, row = m*16 + quad*4 + r.
    #pragma unroll
    for (int m = 0; m < 4; ++m) {
        float pr[4] = {0.f, 0.f, 0.f, 0.f};
        #pragma unroll
        for (int j2 = 0; j2 < 2; ++j2) {
            float waj = wa_r[j2];
            #pragma unroll
            for (int r = 0; r < 4; ++r) {
                float x = acc[m][j2][r] + accV[j2][r];
                float sig = 1.f / (1.f + __expf(-x));
                pr[r] = fmaf(sig, waj, pr[r]);
            }
        }
        #pragma unroll
        for (int r = 0; r < 4; ++r) {
            float vv = pr[r];
            vv += __shfl_xor(vv, 1);
            vv += __shfl_xor(vv, 2);
            vv += __shfl_xor(vv, 4);
            vv += __shfl_xor(vv, 8);
            int row = m * 16 + quad * 4 + r;
            if (col == 0 && row < NN) atomicAdd(&s_alpha[row], vv);
        }
    }
    __syncthreads();   // s_alpha complete

    // ---- 8) session_graph[d] = sum_n cnt[n]*alpha[n]*nodes_f32[n][d]. ----
    if (tid < DD) {
        const int Bd = tid >> 2, od = tid & 3;
        float acc2 = 0.f;
        #pragma unroll 10
        for (int n = 0; n < NN; ++n)
            acc2 = fmaf(s_cnt[n] * s_alpha[n],
                        s_f[n * DD + ((Bd ^ (n & 7)) << 2) + od], acc2);
        out[(size_t)BB * DD + (size_t)b * DD + tid] = acc2;
    }
}

extern "C" void kernel_launch(void* const* d_in, const int* in_sizes, int n_in,
                              void* d_out, int out_size, void* d_ws, size_t ws_size,
                              hipStream_t stream) {
    const int*   seq     = (const int*)  d_in[0];
    const int*   mask    = (const int*)  d_in[1];
    const float* nodes   = (const float*)d_in[2];
    // d_in[3] = batch_size scalar (shapes compile-time fixed)
    const float* W_last  = (const float*)d_in[4];
    const float* W_seq   = (const float*)d_in[5];
    const float* b_seq   = (const float*)d_in[6];
    const float* W_alpha = (const float*)d_in[7];
    float*       out     = (float*)      d_out;

    unsigned short* wsf = (unsigned short*)d_ws;   // 64 KB combined B-fragments

    prep_w<<<16, 256, 0, stream>>>(W_seq, W_last, wsf);
    sess_attn<<<BB, 256, 0, stream>>>(seq, mask, nodes, b_seq, W_alpha, wsf, out);
}